// Round 2
// baseline (1847.955 us; speedup 1.0000x reference)
//
#include <hip/hip_runtime.h>
#include <hip/hip_bf16.h>

// DyGPrompt pretrain: 2-layer temporal graph attention.
//   t   = cos(ts*tw+tb)
//   TQ  = t@q_w.T + bq ; TV = t@v_wE.T + bv
//   [TK/bk eliminated: softmax shift-invariant; sum(attn)=1 pulls TV out]
//   NodeK/V = node_features @ {k,v}_wE.T          (bf16, MFMA)
//   EfK/V   = edge_features[edge_idx]@{k,v}_wDE.T (bf16, MFMA, layer-invariant)
//   attn: scores = q.(NodeK[nb]+EfK), out = sum w*(NodeV[nb]+EfV) + TV
//   layer2 K/V base rows: H1K/V[winner[nb]] if scattered else NodeK/V[nb].

#define NSMP   12000
#define KNB    20
#define EDIM   172
#define HDIM   86
#define NNODES 100000

typedef unsigned int uint;
typedef unsigned short ushort;
typedef __attribute__((ext_vector_type(8))) short  bf16x8;
typedef __attribute__((ext_vector_type(4))) float  f32x4;

static __device__ __forceinline__ ushort f2bf(float f) {
    uint u = __float_as_uint(f);
    uint r = (u + 0x7fffu + ((u >> 16) & 1u)) >> 16;   // RNE, finite inputs
    return (ushort)r;
}
static __device__ __forceinline__ float bf2f(ushort b) {
    return __uint_as_float(((uint)b) << 16);
}

// ---------------- time encoding ----------------
__global__ __launch_bounds__(256) void time_enc_kernel(
    const float* __restrict__ ts, const float* __restrict__ tw,
    const float* __restrict__ tb, float* __restrict__ t)
{
    int i = blockIdx.x * 256 + threadIdx.x;
    if (i < NSMP * EDIM) {
        int b = i / EDIM, e = i - b * EDIM;
        t[i] = cosf(ts[b] * tw[e] + tb[e]);
    }
}

// ---------------- winner scatter (last write wins) ----------------
__global__ __launch_bounds__(256) void winner_init_kernel(int* __restrict__ w)
{
    int i = blockIdx.x * 256 + threadIdx.x;
    if (i < NNODES) w[i] = -1;
}
__global__ __launch_bounds__(256) void winner_scatter_kernel(
    const int* __restrict__ nodes, int* __restrict__ w)
{
    int i = blockIdx.x * 256 + threadIdx.x;
    if (i < NSMP) atomicMax(&w[nodes[i]], i);
}

// ---------------- MFMA GEMM: C = gather(A) @ B^T, dual B, bf16/f32 C -------
// BM=64 rows per block; block loops the 3 N-blocks of 64 (N=172) so the
// (possibly gathered) A tile is staged to LDS exactly once. K=172 padded to
// 192 in LDS (bf16), row stride 200 (+8 pad kills the 16-way frag conflict).
#define LDK 200

static __device__ __forceinline__ void stage16(
    ushort* dst, const float* src, int k0, int Kd)
{
    bf16x8 lo, hi;
    if (src && k0 + 16 <= Kd) {
        const float4 f0 = *(const float4*)(src + k0);
        const float4 f1 = *(const float4*)(src + k0 + 4);
        const float4 f2 = *(const float4*)(src + k0 + 8);
        const float4 f3 = *(const float4*)(src + k0 + 12);
        lo[0]=f2bf(f0.x); lo[1]=f2bf(f0.y); lo[2]=f2bf(f0.z); lo[3]=f2bf(f0.w);
        lo[4]=f2bf(f1.x); lo[5]=f2bf(f1.y); lo[6]=f2bf(f1.z); lo[7]=f2bf(f1.w);
        hi[0]=f2bf(f2.x); hi[1]=f2bf(f2.y); hi[2]=f2bf(f2.z); hi[3]=f2bf(f2.w);
        hi[4]=f2bf(f3.x); hi[5]=f2bf(f3.y); hi[6]=f2bf(f3.z); hi[7]=f2bf(f3.w);
    } else {
        #pragma unroll
        for (int i = 0; i < 8; i++) {
            int ka = k0 + i, kb = k0 + 8 + i;
            lo[i] = (src && ka < Kd) ? f2bf(src[ka]) : (short)0;
            hi[i] = (src && kb < Kd) ? f2bf(src[kb]) : (short)0;
        }
    }
    *(bf16x8*)(dst)     = lo;
    *(bf16x8*)(dst + 8) = hi;
}

__global__ __launch_bounds__(256, 2) void gemm_mfma_nt_kernel(
    const float* __restrict__ A, const int* __restrict__ Aidx, int lda, int M,
    const float* __restrict__ B1, int ldb1, const float* __restrict__ B2, int ldb2,
    const float* __restrict__ bias1, const float* __restrict__ bias2,
    float* __restrict__ C1f, ushort* __restrict__ C1h,
    float* __restrict__ C2f, ushort* __restrict__ C2h,
    int N, int Kd)
{
    __shared__ ushort As [64 * LDK];
    __shared__ ushort Bs1[64 * LDK];
    __shared__ ushort Bs2[64 * LDK];

    const int tid  = threadIdx.x;
    const int wave = tid >> 6;
    const int lane = tid & 63;
    const int col  = lane & 15;
    const int quad = lane >> 4;
    const int m0   = blockIdx.x * 64;
    const bool dual = (B2 != nullptr);

    // ---- stage A tile once (64 rows x 12 chunks of 16)
    for (int task = tid; task < 768; task += 256) {
        int r = task / 12, c = task - r * 12;
        int am = m0 + r;
        const float* src = nullptr;
        if (am < M) {
            long arow = Aidx ? (long)Aidx[am] : (long)am;
            src = A + arow * (long)lda;
        }
        stage16(&As[r * LDK + c * 16], src, c * 16, Kd);
    }

    for (int nb = 0; nb < 3; nb++) {
        const int n0 = nb * 64;
        __syncthreads();   // prev compute done reading Bs (and A staged, iter 0)
        for (int task = tid; task < 768; task += 256) {
            int r = task / 12, c = task - r * 12;
            int bn = n0 + r;
            stage16(&Bs1[r * LDK + c * 16],
                    (bn < N) ? B1 + (long)bn * ldb1 : nullptr, c * 16, Kd);
        }
        if (dual) {
            for (int task = tid; task < 768; task += 256) {
                int r = task / 12, c = task - r * 12;
                int bn = n0 + r;
                stage16(&Bs2[r * LDK + c * 16],
                        (bn < N) ? B2 + (long)bn * ldb2 : nullptr, c * 16, Kd);
            }
        }
        __syncthreads();

        f32x4 z = {0.f, 0.f, 0.f, 0.f};
        f32x4 acc1[4] = {z, z, z, z};
        f32x4 acc2[4] = {z, z, z, z};
        const ushort* b1p = &Bs1[(wave * 16 + col) * LDK];
        const ushort* b2p = &Bs2[(wave * 16 + col) * LDK];
        #pragma unroll
        for (int s = 0; s < 6; s++) {
            const int k = s * 32 + quad * 8;
            bf16x8 bf1 = *(const bf16x8*)(b1p + k);
            bf16x8 bf2 = dual ? *(const bf16x8*)(b2p + k) : bf1;
            #pragma unroll
            for (int mt = 0; mt < 4; mt++) {
                bf16x8 af = *(const bf16x8*)(&As[(mt * 16 + col) * LDK + k]);
                acc1[mt] = __builtin_amdgcn_mfma_f32_16x16x32_bf16(af, bf1, acc1[mt], 0, 0, 0);
                if (dual)
                    acc2[mt] = __builtin_amdgcn_mfma_f32_16x16x32_bf16(af, bf2, acc2[mt], 0, 0, 0);
            }
        }

        const int n = n0 + wave * 16 + col;   // D: col = lane&15
        if (n < N) {
            const float bb1 = bias1 ? bias1[n] : 0.f;
            const float bb2 = bias2 ? bias2[n] : 0.f;
            #pragma unroll
            for (int mt = 0; mt < 4; mt++) {
                #pragma unroll
                for (int r = 0; r < 4; r++) {
                    int m = m0 + mt * 16 + quad * 4 + r;   // D: row = quad*4+reg
                    if (m >= M) continue;
                    long ci = (long)m * N + n;
                    float v1 = acc1[mt][r] + bb1;
                    if (C1f) C1f[ci] = v1; else C1h[ci] = f2bf(v1);
                    if (dual) {
                        float v2 = acc2[mt][r] + bb2;
                        if (C2f) C2f[ci] = v2; else C2h[ci] = f2bf(v2);
                    }
                }
            }
        }
    }
}

// ---------------- f32 GEMM for the small (M=12000) projections -------------
__global__ __launch_bounds__(256) void gemm_nt_kernel(
    const float* __restrict__ A, const int* __restrict__ Aidx, int lda, int M,
    const float* __restrict__ B1, int ldb1, const float* __restrict__ B2, int ldb2,
    const float* __restrict__ bias1, const float* __restrict__ bias2,
    float* __restrict__ C1, float* __restrict__ C2,
    int N, int Kd)
{
    __shared__ __align__(16) float As[16][68];
    __shared__ __align__(16) float Bs1[16][68];
    __shared__ __align__(16) float Bs2[16][68];

    const int t  = threadIdx.x;
    const int tx = t & 15;
    const int ty = t >> 4;
    const int m0 = blockIdx.y * 64;
    const int n0 = blockIdx.x * 64;
    const int lr = t >> 2;
    const int lk = (t & 3) << 2;

    long arow = -1;
    {
        int am = m0 + lr;
        if (am < M) arow = Aidx ? (long)Aidx[am] : (long)am;
    }
    const int  bn   = n0 + lr;
    const bool bok  = bn < N;
    const bool dual = (B2 != nullptr);

    float acc1[4][4] = {};
    float acc2[4][4] = {};

    for (int k0 = 0; k0 < Kd; k0 += 16) {
        const int kb = k0 + lk;
        float4 av  = make_float4(0.f, 0.f, 0.f, 0.f);
        float4 bv1 = av, bv2 = av;
        if (arow >= 0) {
            if (kb + 3 < Kd) av = *(const float4*)(A + arow * (long)lda + kb);
            else { float* p = (float*)&av;
                   for (int i = 0; i < 4; i++) if (kb + i < Kd) p[i] = A[arow * (long)lda + kb + i]; }
        }
        if (bok) {
            if (kb + 3 < Kd) {
                bv1 = *(const float4*)(B1 + (long)bn * ldb1 + kb);
                if (dual) bv2 = *(const float4*)(B2 + (long)bn * ldb2 + kb);
            } else {
                float* p1 = (float*)&bv1; float* p2 = (float*)&bv2;
                for (int i = 0; i < 4; i++) if (kb + i < Kd) {
                    p1[i] = B1[(long)bn * ldb1 + kb + i];
                    if (dual) p2[i] = B2[(long)bn * ldb2 + kb + i];
                }
            }
        }
        __syncthreads();
        {
            const float* pa  = (const float*)&av;
            const float* pb1 = (const float*)&bv1;
            const float* pb2 = (const float*)&bv2;
            for (int i = 0; i < 4; i++) {
                As[lk + i][lr]  = pa[i];
                Bs1[lk + i][lr] = pb1[i];
                if (dual) Bs2[lk + i][lr] = pb2[i];
            }
        }
        __syncthreads();
        #pragma unroll
        for (int kk = 0; kk < 16; kk++) {
            float4 a  = *(const float4*)&As[kk][ty << 2];
            float4 b1 = *(const float4*)&Bs1[kk][tx << 2];
            const float aa[4]  = {a.x, a.y, a.z, a.w};
            const float bb1[4] = {b1.x, b1.y, b1.z, b1.w};
            if (dual) {
                float4 b2 = *(const float4*)&Bs2[kk][tx << 2];
                const float bb2[4] = {b2.x, b2.y, b2.z, b2.w};
                for (int i = 0; i < 4; i++)
                    for (int j = 0; j < 4; j++) {
                        acc1[i][j] += aa[i] * bb1[j];
                        acc2[i][j] += aa[i] * bb2[j];
                    }
            } else {
                for (int i = 0; i < 4; i++)
                    for (int j = 0; j < 4; j++)
                        acc1[i][j] += aa[i] * bb1[j];
            }
        }
    }

    for (int i = 0; i < 4; i++) {
        int m = m0 + (ty << 2) + i;
        if (m >= M) continue;
        for (int j = 0; j < 4; j++) {
            int n = n0 + (tx << 2) + j;
            if (n >= N) continue;
            long ci = (long)m * N + n;
            C1[ci] = acc1[i][j] + (bias1 ? bias1[n] : 0.f);
            if (dual) C2[ci] = acc2[i][j] + (bias2 ? bias2[n] : 0.f);
        }
    }
}

// ---------------- per-sample attention ----------------
#define SKP 176   // padded row stride for sk/sv

__global__ __launch_bounds__(256) void attn_kernel(
    const int* __restrict__ neighbors,
    const float* __restrict__ TQ, const float* __restrict__ TV,
    const float* __restrict__ HQ,
    const int* __restrict__ nodes, const int* __restrict__ winner,
    const ushort* __restrict__ NodeK, const ushort* __restrict__ NodeV,
    const float* __restrict__ H1K, const float* __restrict__ H1V,
    const ushort* __restrict__ EfK, const ushort* __restrict__ EfV,
    float* __restrict__ attn_out)
{
    const int b = blockIdx.x;
    const int t = threadIdx.x;
    __shared__ float sq[SKP];
    __shared__ float sk[KNB * SKP];
    __shared__ float sv[KNB * SKP];
    __shared__ float sw[2][KNB];
    __shared__ int   snb[KNB];
    __shared__ int   spad[KNB];

    if (t < KNB) {
        int nb = neighbors[b * KNB + t];
        snb[t]  = nb;
        spad[t] = (nb == 0) ? 1 : 0;
    }
    if (t < EDIM) {
        float q;
        if (winner) {
            int j = winner[nodes[b]];
            q = HQ[(long)j * EDIM + t] + TQ[(long)b * EDIM + t];
        } else {
            q = HQ[(long)b * EDIM + t] + TQ[(long)b * EDIM + t];
        }
        sq[t] = q;
    }
    __syncthreads();
    if (t == 0) {   // all-padded row: unmask neighbor 0
        int c = 0;
        for (int k = 0; k < KNB; k++) c += spad[k];
        if (c == KNB) spad[0] = 0;
    }

    // stage K/V rows: 20 x 43 chunks of 4
    for (int task = t; task < KNB * 43; task += 256) {
        int kk = task / 43, c = task - kk * 43;
        int e  = c * 4;
        int nb = snb[kk];
        float4 kv, vv;
        bool l2 = false;
        if (winner) {
            int w = winner[nb];
            if (w >= 0) {
                kv = *(const float4*)(H1K + (long)w * EDIM + e);
                vv = *(const float4*)(H1V + (long)w * EDIM + e);
                l2 = true;
            }
        }
        if (!l2) {
            ushort4 kb4 = *(const ushort4*)(NodeK + (long)nb * EDIM + e);
            ushort4 vb4 = *(const ushort4*)(NodeV + (long)nb * EDIM + e);
            kv = make_float4(bf2f(kb4.x), bf2f(kb4.y), bf2f(kb4.z), bf2f(kb4.w));
            vv = make_float4(bf2f(vb4.x), bf2f(vb4.y), bf2f(vb4.z), bf2f(vb4.w));
        }
        long eoff = ((long)b * KNB + kk) * EDIM + e;
        ushort4 ek = *(const ushort4*)(EfK + eoff);
        ushort4 ev = *(const ushort4*)(EfV + eoff);
        float* skp = &sk[kk * SKP + e];
        float* svp = &sv[kk * SKP + e];
        skp[0] = kv.x + bf2f(ek.x); skp[1] = kv.y + bf2f(ek.y);
        skp[2] = kv.z + bf2f(ek.z); skp[3] = kv.w + bf2f(ek.w);
        svp[0] = vv.x + bf2f(ev.x); svp[1] = vv.y + bf2f(ev.y);
        svp[2] = vv.z + bf2f(ev.z); svp[3] = vv.w + bf2f(ev.w);
    }
    __syncthreads();

    // scores: (h,kk) split over 4 lanes each; 160 threads
    if (t < 2 * KNB * 4) {
        int kk = t >> 3, h = (t >> 2) & 1, part = t & 3;
        int d0 = part * 22, d1 = d0 + 22; if (d1 > HDIM) d1 = HDIM;
        const float* qp = &sq[h * HDIM];
        const float* kp = &sk[kk * SKP + h * HDIM];
        float s = 0.f;
        for (int d = d0; d < d1; d++) s += qp[d] * kp[d];
        s += __shfl_xor(s, 1, 64);
        s += __shfl_xor(s, 2, 64);
        if (part == 0)
            sw[h][kk] = spad[kk] ? -1e9f : (s * 0.10783277320343841f);  // 1/sqrt(86)
    }
    __syncthreads();
    if (t < 2) {
        float mx = -1e30f;
        for (int kk = 0; kk < KNB; kk++) mx = fmaxf(mx, sw[t][kk]);
        float sum = 0.f, ex[KNB];
        for (int kk = 0; kk < KNB; kk++) { ex[kk] = expf(sw[t][kk] - mx); sum += ex[kk]; }
        float inv = 1.f / sum;
        for (int kk = 0; kk < KNB; kk++) sw[t][kk] = ex[kk] * inv;
    }
    __syncthreads();
    if (t < EDIM) {
        int h = t / HDIM;
        float acc = 0.f;
        for (int kk = 0; kk < KNB; kk++) acc += sw[h][kk] * sv[kk * SKP + t];
        attn_out[(long)b * EDIM + t] = acc + TV[(long)b * EDIM + t];
    }
}

extern "C" void kernel_launch(void* const* d_in, const int* in_sizes, int n_in,
                              void* d_out, int out_size, void* d_ws, size_t ws_size,
                              hipStream_t stream)
{
    const int*   nodes   = (const int*)d_in[0];
    const float* ts      = (const float*)d_in[1];
    const int*   neigh   = (const int*)d_in[2];
    const int*   edgeidx = (const int*)d_in[3];
    const float* nodef   = (const float*)d_in[4];
    const float* edgef   = (const float*)d_in[5];
    const float* time_w  = (const float*)d_in[6];
    const float* time_b  = (const float*)d_in[7];
    const float* q_w     = (const float*)d_in[8];
    const float* k_w     = (const float*)d_in[9];
    const float* v_w     = (const float*)d_in[10];
    const float* bq      = (const float*)d_in[11];
    const float* bv      = (const float*)d_in[13];
    const float* out_w   = (const float*)d_in[14];
    const float* out_b   = (const float*)d_in[15];
    float* out = (float*)d_out;

    char* wsp = (char*)d_ws;
    size_t off = 0;
    auto alloc = [&](size_t bytes) -> void* {
        void* p = wsp + off;
        off += (bytes + 255) & ~(size_t)255;
        return p;
    };
    const size_t SE = (size_t)NSMP * EDIM;
    float* t_enc = (float*)alloc(SE * 4);
    float* TQ    = (float*)alloc(SE * 4);
    float* TV    = (float*)alloc(SE * 4);
    float* HQ    = (float*)alloc(SE * 4);
    float* AO    = (float*)alloc(SE * 4);
    float* H1    = (float*)alloc(SE * 4);
    float* H1Q   = (float*)alloc(SE * 4);
    float* H1K   = (float*)alloc(SE * 4);
    float* H1V   = (float*)alloc(SE * 4);
    int*   winner = (int*)alloc((size_t)NNODES * 4);
    ushort* NodeK = (ushort*)alloc((size_t)NNODES * EDIM * 2);
    ushort* NodeV = (ushort*)alloc((size_t)NNODES * EDIM * 2);
    ushort* EfK   = (ushort*)alloc((size_t)NSMP * KNB * EDIM * 2);
    ushort* EfV   = (ushort*)alloc((size_t)NSMP * KNB * EDIM * 2);
    if (off > ws_size) return;

    const int ldkw = 2 * EDIM;  // 344
    dim3 blk(256);
    dim3 gB((EDIM + 63) / 64, (NSMP + 63) / 64);

    time_enc_kernel<<<(NSMP * EDIM + 255) / 256, blk, 0, stream>>>(ts, time_w, time_b, t_enc);

    // TQ = t@q_w.T + bq ; TV = t@v_wE.T + bv   (dual, different ldb)
    gemm_nt_kernel<<<gB, blk, 0, stream>>>(t_enc, nullptr, EDIM, NSMP,
        q_w, EDIM, v_w, ldkw, bq, bv, TQ, TV, EDIM, EDIM);
    // NodeK/V (bf16, MFMA)
    gemm_mfma_nt_kernel<<<(NNODES + 63) / 64, blk, 0, stream>>>(
        nodef, nullptr, EDIM, NNODES,
        k_w, ldkw, v_w, ldkw, nullptr, nullptr,
        nullptr, NodeK, nullptr, NodeV, EDIM, EDIM);
    // EfK/V (bf16, MFMA, gathered A)
    gemm_mfma_nt_kernel<<<(NSMP * KNB + 63) / 64, blk, 0, stream>>>(
        edgef, edgeidx, EDIM, NSMP * KNB,
        k_w + EDIM, ldkw, v_w + EDIM, ldkw, nullptr, nullptr,
        nullptr, EfK, nullptr, EfV, EDIM, EDIM);
    // HQ = nf[nodes]@q_w.T
    gemm_nt_kernel<<<gB, blk, 0, stream>>>(nodef, nodes, EDIM, NSMP,
        q_w, EDIM, nullptr, 0, nullptr, nullptr, HQ, nullptr, EDIM, EDIM);

    // layer 1 attention
    attn_kernel<<<NSMP, blk, 0, stream>>>(neigh, TQ, TV, HQ,
        nullptr, nullptr, NodeK, NodeV, nullptr, nullptr, EfK, EfV, AO);
    // h1 = AO@out_w.T + out_b
    gemm_nt_kernel<<<gB, blk, 0, stream>>>(AO, nullptr, EDIM, NSMP,
        out_w, EDIM, nullptr, 0, out_b, nullptr, H1, nullptr, EDIM, EDIM);

    winner_init_kernel<<<(NNODES + 255) / 256, blk, 0, stream>>>(winner);
    winner_scatter_kernel<<<(NSMP + 255) / 256, blk, 0, stream>>>(nodes, winner);

    // layer-2 projections of h1
    gemm_nt_kernel<<<gB, blk, 0, stream>>>(H1, nullptr, EDIM, NSMP,
        q_w, EDIM, nullptr, 0, nullptr, nullptr, H1Q, nullptr, EDIM, EDIM);
    gemm_nt_kernel<<<gB, blk, 0, stream>>>(H1, nullptr, EDIM, NSMP,
        k_w, ldkw, v_w, ldkw, nullptr, nullptr, H1K, H1V, EDIM, EDIM);

    // layer 2 attention
    attn_kernel<<<NSMP, blk, 0, stream>>>(neigh, TQ, TV, H1Q,
        nodes, winner, NodeK, NodeV, H1K, H1V, EfK, EfV, AO);
    // final -> d_out
    gemm_nt_kernel<<<gB, blk, 0, stream>>>(AO, nullptr, EDIM, NSMP,
        out_w, EDIM, nullptr, 0, out_b, nullptr, out, nullptr, EDIM, EDIM);
}

// Round 3
// 953.890 us; speedup vs baseline: 1.9373x; 1.9373x over previous
//
#include <hip/hip_runtime.h>
#include <hip/hip_bf16.h>

// DyGPrompt pretrain: 2-layer temporal graph attention.
//   t   = cos(ts*tw+tb)
//   TQ  = t@q_w.T + bq ; TV = t@v_wE.T + bv
//   [TK/bk eliminated: softmax shift-invariant; sum(attn)=1 pulls TV out]
//   NodeK/V = node_features @ {k,v}_wE.T          (bf16, MFMA)
//   EfK/V   = edge_features[edge_idx]@{k,v}_wDE.T (bf16, MFMA, layer-invariant)
//   attn: scores = q.(NodeK[nb]+EfK), out = sum w*(NodeV[nb]+EfV) + TV
//   layer2 K/V base rows: H1K/V[winner[nb]] if scattered else NodeK/V[nb].
// All GEMMs: register-fragment MFMA, weights pre-swizzled to bf16 B-fragment
// layout (6 tables, 405 KB, L2-resident). No LDS, no barriers in GEMM.

#define NSMP   12000
#define KNB    20
#define EDIM   172
#define HDIM   86
#define NNODES 100000
#define NT_N   11     // ceil(172/16) n-tiles
#define KS_N   6      // ceil(172/32) k-steps
#define TBL_SZ (NT_N * KS_N * 64 * 8)   // elements per pre-swizzled table

typedef unsigned int uint;
typedef unsigned short ushort;
typedef __attribute__((ext_vector_type(8))) short  bf16x8;
typedef __attribute__((ext_vector_type(4))) float  f32x4;

static __device__ __forceinline__ ushort f2bf(float f) {
    uint u = __float_as_uint(f);
    uint r = (u + 0x7fffu + ((u >> 16) & 1u)) >> 16;   // RNE, finite inputs
    return (ushort)r;
}
static __device__ __forceinline__ float bf2f(ushort b) {
    return __uint_as_float(((uint)b) << 16);
}

// ---------------- time encoding ----------------
__global__ __launch_bounds__(256) void time_enc_kernel(
    const float* __restrict__ ts, const float* __restrict__ tw,
    const float* __restrict__ tb, float* __restrict__ t)
{
    int i = blockIdx.x * 256 + threadIdx.x;
    if (i < NSMP * EDIM) {
        int b = i / EDIM, e = i - b * EDIM;
        t[i] = cosf(ts[b] * tw[e] + tb[e]);
    }
}

// ---------------- winner scatter (last write wins) ----------------
__global__ __launch_bounds__(256) void winner_init_kernel(int* __restrict__ w)
{
    int i = blockIdx.x * 256 + threadIdx.x;
    if (i < NNODES) w[i] = -1;
}
__global__ __launch_bounds__(256) void winner_scatter_kernel(
    const int* __restrict__ nodes, int* __restrict__ w)
{
    int i = blockIdx.x * 256 + threadIdx.x;
    if (i < NSMP) atomicMax(&w[nodes[i]], i);
}

// ---------------- weight pre-swizzle: f32 row-major -> bf16 B-fragments ----
// Table layout: frag (nt,s,lane) at ((nt*KS_N+s)*64+lane)*8, 8 bf16 each:
//   elem j = W[nt*16 + (lane&15)][koff + s*32 + (lane>>4)*8 + j]  (0 if OOB)
// Tables: 0=q_w 1=out_w 2=k_w[:, :172] 3=k_w[:, 172:] 4=v_w[:, :172] 5=v_w[:, 172:]
__global__ __launch_bounds__(256) void preswizzle_kernel(
    const float* __restrict__ q_w, const float* __restrict__ out_w,
    const float* __restrict__ k_w, const float* __restrict__ v_w,
    ushort* __restrict__ BF)
{
    int gid = blockIdx.x * 256 + threadIdx.x;             // one frag per thread
    int total = 6 * NT_N * KS_N * 64;
    if (gid >= total) return;
    int tbl  = gid / (NT_N * KS_N * 64);
    int rem  = gid - tbl * (NT_N * KS_N * 64);
    int lane = rem & 63;
    int fs   = rem >> 6;          // nt*KS_N + s
    int s    = fs % KS_N;
    int nt   = fs / KS_N;

    const float* src; int ldb, koff;
    switch (tbl) {
        case 0: src = q_w;   ldb = EDIM;     koff = 0;    break;
        case 1: src = out_w; ldb = EDIM;     koff = 0;    break;
        case 2: src = k_w;   ldb = 2 * EDIM; koff = 0;    break;
        case 3: src = k_w;   ldb = 2 * EDIM; koff = EDIM; break;
        case 4: src = v_w;   ldb = 2 * EDIM; koff = 0;    break;
        default: src = v_w;  ldb = 2 * EDIM; koff = EDIM; break;
    }
    int n  = nt * 16 + (lane & 15);
    int k0 = s * 32 + (lane >> 4) * 8;
    ushort* dst = BF + (size_t)tbl * TBL_SZ + (size_t)(fs * 64 + lane) * 8;
    #pragma unroll
    for (int j = 0; j < 8; j++) {
        int k = k0 + j;
        dst[j] = (n < EDIM && k < EDIM) ? f2bf(src[(long)n * ldb + koff + k]) : (ushort)0;
    }
}

// ---------------- register-fragment MFMA GEMM: C = gather(A) @ W^T ---------
// A: f32 row-major lda=172, M % 16 == 0. Wave owns 16 rows, no LDS/barriers.
// BF1/BF2: pre-swizzled bf16 tables. C: f32 or bf16 per output.
__global__ __launch_bounds__(256) void gemm_rf_kernel(
    const float* __restrict__ A, const int* __restrict__ Aidx, int M,
    const ushort* __restrict__ BF1, const ushort* __restrict__ BF2,
    const float* __restrict__ bias1, const float* __restrict__ bias2,
    float* __restrict__ C1f, ushort* __restrict__ C1h,
    float* __restrict__ C2f, ushort* __restrict__ C2h)
{
    const int lane = threadIdx.x & 63;
    const int wave = threadIdx.x >> 6;
    const int col  = lane & 15;
    const int quad = lane >> 4;
    const int m0   = blockIdx.x * 64 + wave * 16;
    if (m0 >= M) return;                      // whole-wave guard (M%16==0)
    const bool dual = (BF2 != nullptr);

    long arow = m0 + col;
    if (Aidx) arow = (long)Aidx[arow];
    const float* ap = A + arow * EDIM + quad * 8;

    // A-fragments: row = lane&15, k = quad*8 + j  (within 32-wide k-step)
    bf16x8 af[KS_N];
    #pragma unroll
    for (int s = 0; s < KS_N - 1; s++) {
        float4 f0 = *(const float4*)(ap + s * 32);
        float4 f1 = *(const float4*)(ap + s * 32 + 4);
        af[s][0] = f2bf(f0.x); af[s][1] = f2bf(f0.y);
        af[s][2] = f2bf(f0.z); af[s][3] = f2bf(f0.w);
        af[s][4] = f2bf(f1.x); af[s][5] = f2bf(f1.y);
        af[s][6] = f2bf(f1.z); af[s][7] = f2bf(f1.w);
    }
    {   // last k-step: k = 160 + quad*8 + j, guard k < 172
        const int kb = 160 + quad * 8;
        #pragma unroll
        for (int j = 0; j < 8; j++)
            af[KS_N - 1][j] = (kb + j < EDIM) ? f2bf(ap[160 + j]) : (short)0;
    }

    #pragma unroll
    for (int nt = 0; nt < NT_N; nt++) {
        const ushort* bp1 = BF1 + (size_t)(nt * KS_N * 64 + lane) * 8;
        bf16x8 bf1[KS_N];
        #pragma unroll
        for (int s = 0; s < KS_N; s++)
            bf1[s] = *(const bf16x8*)(bp1 + (size_t)s * 64 * 8);
        f32x4 acc1 = {0.f, 0.f, 0.f, 0.f};
        f32x4 acc2 = {0.f, 0.f, 0.f, 0.f};
        if (dual) {
            const ushort* bp2 = BF2 + (size_t)(nt * KS_N * 64 + lane) * 8;
            bf16x8 bf2[KS_N];
            #pragma unroll
            for (int s = 0; s < KS_N; s++)
                bf2[s] = *(const bf16x8*)(bp2 + (size_t)s * 64 * 8);
            #pragma unroll
            for (int s = 0; s < KS_N; s++) {
                acc1 = __builtin_amdgcn_mfma_f32_16x16x32_bf16(af[s], bf1[s], acc1, 0, 0, 0);
                acc2 = __builtin_amdgcn_mfma_f32_16x16x32_bf16(af[s], bf2[s], acc2, 0, 0, 0);
            }
        } else {
            #pragma unroll
            for (int s = 0; s < KS_N; s++)
                acc1 = __builtin_amdgcn_mfma_f32_16x16x32_bf16(af[s], bf1[s], acc1, 0, 0, 0);
        }

        const int n = nt * 16 + col;          // C/D: col = lane&15
        if (n < EDIM) {
            const float bb1 = bias1 ? bias1[n] : 0.f;
            #pragma unroll
            for (int r = 0; r < 4; r++) {     // C/D: row = quad*4 + r
                long ci = (long)(m0 + quad * 4 + r) * EDIM + n;
                float v1 = acc1[r] + bb1;
                if (C1f) C1f[ci] = v1; else C1h[ci] = f2bf(v1);
            }
            if (dual) {
                const float bb2 = bias2 ? bias2[n] : 0.f;
                #pragma unroll
                for (int r = 0; r < 4; r++) {
                    long ci = (long)(m0 + quad * 4 + r) * EDIM + n;
                    float v2 = acc2[r] + bb2;
                    if (C2f) C2f[ci] = v2; else C2h[ci] = f2bf(v2);
                }
            }
        }
    }
}

// ---------------- per-sample attention ----------------
#define SKP 176   // padded row stride for sk/sv

__global__ __launch_bounds__(256) void attn_kernel(
    const int* __restrict__ neighbors,
    const float* __restrict__ TQ, const float* __restrict__ TV,
    const float* __restrict__ HQ,
    const int* __restrict__ nodes, const int* __restrict__ winner,
    const ushort* __restrict__ NodeK, const ushort* __restrict__ NodeV,
    const float* __restrict__ H1K, const float* __restrict__ H1V,
    const ushort* __restrict__ EfK, const ushort* __restrict__ EfV,
    float* __restrict__ attn_out)
{
    const int b = blockIdx.x;
    const int t = threadIdx.x;
    __shared__ float sq[SKP];
    __shared__ float sk[KNB * SKP];
    __shared__ float sv[KNB * SKP];
    __shared__ float sw[2][KNB];
    __shared__ int   snb[KNB];
    __shared__ int   spad[KNB];

    if (t < KNB) {
        int nb = neighbors[b * KNB + t];
        snb[t]  = nb;
        spad[t] = (nb == 0) ? 1 : 0;
    }
    if (t < EDIM) {
        float q;
        if (winner) {
            int j = winner[nodes[b]];
            q = HQ[(long)j * EDIM + t] + TQ[(long)b * EDIM + t];
        } else {
            q = HQ[(long)b * EDIM + t] + TQ[(long)b * EDIM + t];
        }
        sq[t] = q;
    }
    __syncthreads();
    if (t == 0) {   // all-padded row: unmask neighbor 0
        int c = 0;
        for (int k = 0; k < KNB; k++) c += spad[k];
        if (c == KNB) spad[0] = 0;
    }

    // stage K/V rows: 20 x 43 chunks of 4
    for (int task = t; task < KNB * 43; task += 256) {
        int kk = task / 43, c = task - kk * 43;
        int e  = c * 4;
        int nb = snb[kk];
        float4 kv, vv;
        bool l2 = false;
        if (winner) {
            int w = winner[nb];
            if (w >= 0) {
                kv = *(const float4*)(H1K + (long)w * EDIM + e);
                vv = *(const float4*)(H1V + (long)w * EDIM + e);
                l2 = true;
            }
        }
        if (!l2) {
            ushort4 kb4 = *(const ushort4*)(NodeK + (long)nb * EDIM + e);
            ushort4 vb4 = *(const ushort4*)(NodeV + (long)nb * EDIM + e);
            kv = make_float4(bf2f(kb4.x), bf2f(kb4.y), bf2f(kb4.z), bf2f(kb4.w));
            vv = make_float4(bf2f(vb4.x), bf2f(vb4.y), bf2f(vb4.z), bf2f(vb4.w));
        }
        long eoff = ((long)b * KNB + kk) * EDIM + e;
        ushort4 ek = *(const ushort4*)(EfK + eoff);
        ushort4 ev = *(const ushort4*)(EfV + eoff);
        float* skp = &sk[kk * SKP + e];
        float* svp = &sv[kk * SKP + e];
        skp[0] = kv.x + bf2f(ek.x); skp[1] = kv.y + bf2f(ek.y);
        skp[2] = kv.z + bf2f(ek.z); skp[3] = kv.w + bf2f(ek.w);
        svp[0] = vv.x + bf2f(ev.x); svp[1] = vv.y + bf2f(ev.y);
        svp[2] = vv.z + bf2f(ev.z); svp[3] = vv.w + bf2f(ev.w);
    }
    __syncthreads();

    // scores: (h,kk) split over 4 lanes each; 160 threads
    if (t < 2 * KNB * 4) {
        int kk = t >> 3, h = (t >> 2) & 1, part = t & 3;
        int d0 = part * 22, d1 = d0 + 22; if (d1 > HDIM) d1 = HDIM;
        const float* qp = &sq[h * HDIM];
        const float* kp = &sk[kk * SKP + h * HDIM];
        float s = 0.f;
        for (int d = d0; d < d1; d++) s += qp[d] * kp[d];
        s += __shfl_xor(s, 1, 64);
        s += __shfl_xor(s, 2, 64);
        if (part == 0)
            sw[h][kk] = spad[kk] ? -1e9f : (s * 0.10783277320343841f);  // 1/sqrt(86)
    }
    __syncthreads();
    if (t < 2) {
        float mx = -1e30f;
        for (int kk = 0; kk < KNB; kk++) mx = fmaxf(mx, sw[t][kk]);
        float sum = 0.f, ex[KNB];
        for (int kk = 0; kk < KNB; kk++) { ex[kk] = expf(sw[t][kk] - mx); sum += ex[kk]; }
        float inv = 1.f / sum;
        for (int kk = 0; kk < KNB; kk++) sw[t][kk] = ex[kk] * inv;
    }
    __syncthreads();
    if (t < EDIM) {
        int h = t / HDIM;
        float acc = 0.f;
        for (int kk = 0; kk < KNB; kk++) acc += sw[h][kk] * sv[kk * SKP + t];
        attn_out[(long)b * EDIM + t] = acc + TV[(long)b * EDIM + t];
    }
}

extern "C" void kernel_launch(void* const* d_in, const int* in_sizes, int n_in,
                              void* d_out, int out_size, void* d_ws, size_t ws_size,
                              hipStream_t stream)
{
    const int*   nodes   = (const int*)d_in[0];
    const float* ts      = (const float*)d_in[1];
    const int*   neigh   = (const int*)d_in[2];
    const int*   edgeidx = (const int*)d_in[3];
    const float* nodef   = (const float*)d_in[4];
    const float* edgef   = (const float*)d_in[5];
    const float* time_w  = (const float*)d_in[6];
    const float* time_b  = (const float*)d_in[7];
    const float* q_w     = (const float*)d_in[8];
    const float* k_w     = (const float*)d_in[9];
    const float* v_w     = (const float*)d_in[10];
    const float* bq      = (const float*)d_in[11];
    const float* bv      = (const float*)d_in[13];
    const float* out_w   = (const float*)d_in[14];
    const float* out_b   = (const float*)d_in[15];
    float* out = (float*)d_out;

    char* wsp = (char*)d_ws;
    size_t off = 0;
    auto alloc = [&](size_t bytes) -> void* {
        void* p = wsp + off;
        off += (bytes + 255) & ~(size_t)255;
        return p;
    };
    const size_t SE = (size_t)NSMP * EDIM;
    float* t_enc = (float*)alloc(SE * 4);
    float* TQ    = (float*)alloc(SE * 4);
    float* TV    = (float*)alloc(SE * 4);
    float* HQ    = (float*)alloc(SE * 4);
    float* AO    = (float*)alloc(SE * 4);
    float* H1    = (float*)alloc(SE * 4);
    float* H1Q   = (float*)alloc(SE * 4);
    float* H1K   = (float*)alloc(SE * 4);
    float* H1V   = (float*)alloc(SE * 4);
    int*   winner = (int*)alloc((size_t)NNODES * 4);
    ushort* NodeK = (ushort*)alloc((size_t)NNODES * EDIM * 2);
    ushort* NodeV = (ushort*)alloc((size_t)NNODES * EDIM * 2);
    ushort* EfK   = (ushort*)alloc((size_t)NSMP * KNB * EDIM * 2);
    ushort* EfV   = (ushort*)alloc((size_t)NSMP * KNB * EDIM * 2);
    ushort* BF    = (ushort*)alloc((size_t)6 * TBL_SZ * 2);
    if (off > ws_size) return;

    const ushort* BFq   = BF + 0 * TBL_SZ;
    const ushort* BFout = BF + 1 * TBL_SZ;
    const ushort* BFkE  = BF + 2 * TBL_SZ;
    const ushort* BFkDE = BF + 3 * TBL_SZ;
    const ushort* BFvE  = BF + 4 * TBL_SZ;
    const ushort* BFvDE = BF + 5 * TBL_SZ;

    dim3 blk(256);
    const int gS = (NSMP + 63) / 64;            // 188 (M=12000, %16==0)

    preswizzle_kernel<<<(6 * NT_N * KS_N * 64 + 255) / 256, blk, 0, stream>>>(
        q_w, out_w, k_w, v_w, BF);
    time_enc_kernel<<<(NSMP * EDIM + 255) / 256, blk, 0, stream>>>(ts, time_w, time_b, t_enc);

    // TQ = t@q_w.T + bq ; TV = t@v_wE.T + bv
    gemm_rf_kernel<<<gS, blk, 0, stream>>>(t_enc, nullptr, NSMP,
        BFq, BFvE, bq, bv, TQ, nullptr, TV, nullptr);
    // NodeK/V (bf16 out)
    gemm_rf_kernel<<<(NNODES + 63) / 64, blk, 0, stream>>>(nodef, nullptr, NNODES,
        BFkE, BFvE, nullptr, nullptr, nullptr, NodeK, nullptr, NodeV);
    // EfK/V (gathered A, bf16 out)
    gemm_rf_kernel<<<(NSMP * KNB + 63) / 64, blk, 0, stream>>>(edgef, edgeidx, NSMP * KNB,
        BFkDE, BFvDE, nullptr, nullptr, nullptr, EfK, nullptr, EfV);
    // HQ = nf[nodes]@q_w.T (bias via TQ)
    gemm_rf_kernel<<<gS, blk, 0, stream>>>(nodef, nodes, NSMP,
        BFq, nullptr, nullptr, nullptr, HQ, nullptr, nullptr, nullptr);

    // layer 1 attention
    attn_kernel<<<NSMP, blk, 0, stream>>>(neigh, TQ, TV, HQ,
        nullptr, nullptr, NodeK, NodeV, nullptr, nullptr, EfK, EfV, AO);
    // h1 = AO@out_w.T + out_b
    gemm_rf_kernel<<<gS, blk, 0, stream>>>(AO, nullptr, NSMP,
        BFout, nullptr, out_b, nullptr, H1, nullptr, nullptr, nullptr);

    winner_init_kernel<<<(NNODES + 255) / 256, blk, 0, stream>>>(winner);
    winner_scatter_kernel<<<(NSMP + 255) / 256, blk, 0, stream>>>(nodes, winner);

    // layer-2 projections of h1
    gemm_rf_kernel<<<gS, blk, 0, stream>>>(H1, nullptr, NSMP,
        BFq, nullptr, nullptr, nullptr, H1Q, nullptr, nullptr, nullptr);
    gemm_rf_kernel<<<gS, blk, 0, stream>>>(H1, nullptr, NSMP,
        BFkE, BFvE, nullptr, nullptr, H1K, nullptr, H1V, nullptr);

    // layer 2 attention
    attn_kernel<<<NSMP, blk, 0, stream>>>(neigh, TQ, TV, H1Q,
        nodes, winner, NodeK, NodeV, H1K, H1V, EfK, EfV, AO);
    // final -> d_out
    gemm_rf_kernel<<<gS, blk, 0, stream>>>(AO, nullptr, NSMP,
        BFout, nullptr, out_b, nullptr, out, nullptr, nullptr, nullptr);
}